// Round 4
// baseline (26.006 us; speedup 1.0000x reference)
//
#include <hip/hip_runtime.h>
#include <stdint.h>

#define M_MACH 50
#define N_JOBS 100
#define NFEAT 5400        // 50*4 + 100*2 + 50*100
#define A_DIM 32
#define C_DIM 1000
#define INIT_T 16

// One LANE per clause. Screen features 0..15 (machine-time bits of machines
// 0..3) with packed-byte compares: per lane, load 16 B of each plane, select
// bytes by the byte-replicated feature mask, and test "any byte > 16" with
// the carry trick. P(clause survives 16 random features) ~ 2.5e-5 -> about
// one survivor per call takes the per-lane serial full scan (early exit,
// expected ~2 more features). 500 waves total, no ballots in the hot path.
__global__ __launch_bounds__(256) void policy_kernel(
    const float* __restrict__ state,
    const int8_t* __restrict__ ta,
    const int8_t* __restrict__ sign,
    float* __restrict__ out) {
    const int lane = threadIdx.x & 63;
    const int wid  = threadIdx.x >> 6;
    const int q    = (blockIdx.x * 4 + wid) * 64 + lane;   // clause 0..31999

    const int8_t* base = ta + (size_t)q * (2 * NFEAT);
    // Issue both plane loads first (4 x 8B, all 8B-aligned: 10800%16==0,
    // 5400%8==0). Independent of the feature bits computed below.
    const uint64_t in01 = *reinterpret_cast<const uint64_t*>(base);
    const uint64_t in23 = *reinterpret_cast<const uint64_t*>(base + 8);
    const uint64_t ex01 = *reinterpret_cast<const uint64_t*>(base + NFEAT);
    const uint64_t ex23 = *reinterpret_cast<const uint64_t*>(base + NFEAT + 8);

    // Wave-wide max over state[0..49] (overlaps load latency).
    const float v0 = (lane < M_MACH) ? state[lane] : -1.0f;
    float mx = v0;
    #pragma unroll
    for (int off = 1; off < 64; off <<= 1)
        mx = fmaxf(mx, __shfl_xor(mx, off, 64));

    // Feature bits 0..15: lane j<16 computes bit for machine j>>2, bit j&3.
    bool mybit = false;
    if (lane < 16) {
        const float s = __shfl(v0, lane >> 2, 64);
        const int n = (mx > 0.0f) ? (int)((s / mx) * 15.0f) : 0;
        mybit = (n >> (lane & 3)) & 1;
    }
    const uint32_t mask16 = (uint32_t)(__ballot(mybit) & 0xFFFFull);

    // Byte-replicate the 16 bits into 4 dword masks (0x00/0xFF per byte).
    uint32_t M[4];
    #pragma unroll
    for (int d = 0; d < 4; ++d) {
        const uint32_t nib = (mask16 >> (4 * d)) & 0xFu;
        M[d] = ((nib * 0x00204081u) & 0x01010101u) * 0xFFu;
    }

    const uint32_t in_d[4] = { (uint32_t)in01, (uint32_t)(in01 >> 32),
                               (uint32_t)in23, (uint32_t)(in23 >> 32) };
    const uint32_t ex_d[4] = { (uint32_t)ex01, (uint32_t)(ex01 >> 32),
                               (uint32_t)ex23, (uint32_t)(ex23 >> 32) };

    // sel byte = bit ? exclude : include ; flag bytes > 16 via carry trick.
    uint32_t acc = 0;
    #pragma unroll
    for (int d = 0; d < 4; ++d) {
        const uint32_t sel = (in_d[d] & ~M[d]) | (ex_d[d] & M[d]);
        acc |= ((sel & 0x7F7F7F7Fu) + 0x6F6F6F6Fu) | sel;
    }
    bool violated = (acc & 0x80808080u) != 0u;

    int val = 0;
    if (!violated) {
        // Rare path (~1 lane per call): serial scan of features 16..5399
        // with early exit (expected ~2 iterations for a random survivor).
        bool bad = false;
        for (int f = 16; f < NFEAT && !bad; ++f) {
            int b;
            if (f < M_MACH * 4) {
                const int n = (mx > 0.0f)
                    ? (int)((state[f >> 2] / mx) * 15.0f) : 0;
                b = (n >> (f & 3)) & 1;
            } else if (f < M_MACH * 4 + N_JOBS * 2) {
                const int rel = f - M_MACH * 4;
                int st = (int)(state[M_MACH + (rel >> 1)] * 3.0f);
                if (st > 3) st = 3;
                b = (st >> (rel & 1)) & 1;
            } else {
                b = (int)state[M_MACH + N_JOBS + (f - (M_MACH*4 + N_JOBS*2))];
            }
            bad = ((b ? base[NFEAT + f] : base[f]) > INIT_T);
        }
        if (!bad) val = (int)sign[q];
    }
    if (val != 0) atomicAdd(&out[q / C_DIM], (float)val);
}

extern "C" void kernel_launch(void* const* d_in, const int* in_sizes, int n_in,
                              void* d_out, int out_size, void* d_ws, size_t ws_size,
                              hipStream_t stream) {
    const float*  state = (const float*)d_in[0];
    const int8_t* ta    = (const int8_t*)d_in[1];
    const int8_t* sign  = (const int8_t*)d_in[2];
    float* out = (float*)d_out;

    // Atomics below need zeros; harness doesn't re-poison between replays.
    hipMemsetAsync(out, 0, out_size * sizeof(float), stream);

    // 125 blocks x 4 waves x 64 lanes = 32000 lanes, one clause each.
    policy_kernel<<<125, 256, 0, stream>>>(state, ta, sign, out);
}

// Round 5
// 13.731 us; speedup vs baseline: 1.8939x; 1.8939x over previous
//
#include <hip/hip_runtime.h>
#include <stdint.h>

#define M_MACH 50
#define N_JOBS 100
#define NFEAT 5400        // 50*4 + 100*2 + 50*100
#define A_DIM 32
#define C_DIM 1000
#define INIT_T 16
#define WPB 8             // waves per block (512 threads)

// Two clauses per wave: lanes 0..31 screen clause A (features 0..31), lanes
// 32..63 screen clause B. Each plane load is two contiguous 32B segments ->
// fully coalesced. One 64-bit ballot yields both verdicts. P(clause survives
// 32 random features) ~ 6e-10 -> rare path never taken with this data but
// kept for correctness (whole-wave scan, early exit).
__global__ __launch_bounds__(512) void policy_kernel(
    const float* __restrict__ state,
    const int8_t* __restrict__ ta,
    const int8_t* __restrict__ sign,
    float* __restrict__ out) {
    const int lane = threadIdx.x & 63;
    const int wid  = threadIdx.x >> 6;
    const int sub  = lane & 31;                    // feature index 0..31
    const int half = lane >> 5;                    // 0 = clause A, 1 = clause B
    const int q0   = (blockIdx.x * WPB + wid) * 2; // clauses q0, q0+1
    const int q    = q0 + half;

    const int8_t* base = ta + (size_t)q * (2 * NFEAT);
    // Issue both plane loads immediately (independent of feature bits).
    const int inb = base[sub];
    const int exb = base[NFEAT + sub];

    // Wave-wide max over state[0..49] (overlaps load latency).
    const float v0 = (lane < M_MACH) ? state[lane] : -1.0f;
    float mx = v0;
    #pragma unroll
    for (int off = 1; off < 64; off <<= 1)
        mx = fmaxf(mx, __shfl_xor(mx, off, 64));

    // Feature bit for f = sub: machine i = sub>>2 (0..7), bit k = sub&3.
    const float s_i = __shfl(v0, sub >> 2, 64);
    const int norm  = (mx > 0.0f) ? (int)((s_i / mx) * 15.0f) : 0;
    const bool bit  = (norm >> (sub & 3)) & 1;

    const unsigned long long ball = __ballot((bit ? exb : inb) > INIT_T);
    const bool violated = half ? (ball >> 32) != 0ull
                               : (ball & 0xFFFFFFFFull) != 0ull;

    // Rare full-scan path (whole wave cooperates per surviving clause).
    bool ok = !violated;
    #pragma unroll 1
    for (int j = 0; j < 2; ++j) {
        const bool need = __shfl(ok ? 1 : 0, j * 32, 64);
        if (!need) continue;
        const int qq = q0 + j;
        const int8_t* b0 = ta + (size_t)qq * (2 * NFEAT);
        bool viol = false;
        for (int f0 = 32; f0 < NFEAT && !viol; f0 += 64) {
            const int f = f0 + lane;
            bool vv = false;
            if (f < NFEAT) {
                int b2;
                if (f < M_MACH * 4) {
                    const int n2 = (mx > 0.0f)
                        ? (int)((state[f >> 2] / mx) * 15.0f) : 0;
                    b2 = (n2 >> (f & 3)) & 1;
                } else if (f < M_MACH * 4 + N_JOBS * 2) {
                    const int rel = f - M_MACH * 4;
                    int st = (int)(state[M_MACH + (rel >> 1)] * 3.0f);
                    if (st > 3) st = 3;
                    b2 = (st >> (rel & 1)) & 1;
                } else {
                    b2 = (int)state[M_MACH + N_JOBS + (f - (M_MACH*4 + N_JOBS*2))];
                }
                vv = ((b2 ? b0[NFEAT + f] : b0[f]) > INIT_T);
            }
            viol = __any(vv);
        }
        if (viol && half == j) ok = false;
    }

    // One atomic per surviving clause (essentially none with this data).
    if (ok && sub == 0) atomicAdd(&out[q / C_DIM], (float)sign[q]);
}

extern "C" void kernel_launch(void* const* d_in, const int* in_sizes, int n_in,
                              void* d_out, int out_size, void* d_ws, size_t ws_size,
                              hipStream_t stream) {
    const float*  state = (const float*)d_in[0];
    const int8_t* ta    = (const int8_t*)d_in[1];
    const int8_t* sign  = (const int8_t*)d_in[2];
    float* out = (float*)d_out;

    // Atomics need zeros; harness doesn't re-poison between replays.
    hipMemsetAsync(out, 0, out_size * sizeof(float), stream);

    // 2000 blocks x 8 waves x 2 clauses = 32000 clauses.
    policy_kernel<<<2000, 512, 0, stream>>>(state, ta, sign, out);
}